// Round 1
// baseline (759.003 us; speedup 1.0000x reference)
//
#include <hip/hip_runtime.h>

// TemporalTransformerConv on MI355X.
// Algebraic collapse: node/edge GEMMs fold into attn vectors since the
// message value el_prime is scalar-per-head. Single streaming pass over the
// 320 MB edge features is the memory floor (~51 us at 6.3 TB/s).

constexpr int F = 100;           // NODE_F == EDGE_F == TIME_D == OUT_F
constexpr float NEG_SLOPE = 0.2f;

__device__ __forceinline__ float wave_reduce(float v) {
#pragma unroll
    for (int off = 32; off > 0; off >>= 1)
        v += __shfl_down(v, off, 64);
    return v;
}

// K0: fold fc_* weights through attn vectors.
// wave wid < 100          -> w_node[wid] = {wl0, wl1, wr0, wr1}
// wave 100 <= wid < 300   -> w_edge[wid-100] = {we0, we1}
// wave 300+j (j<6)        -> bias[j] = {bl0, bl1, br0, br1, be0, be1}[j]
__global__ void precompute_kernel(
    const float* __restrict__ fc_node_w, const float* __restrict__ fc_node_b,
    const float* __restrict__ fc_edge_w, const float* __restrict__ fc_edge_b,
    const float* __restrict__ attn_l, const float* __restrict__ attn_r,
    const float* __restrict__ attn_e,
    float4* __restrict__ w_node, float2* __restrict__ w_edge,
    float* __restrict__ bias)
{
    int wid  = blockIdx.x * (blockDim.x >> 6) + (threadIdx.x >> 6);
    int lane = threadIdx.x & 63;
    if (wid < F) {
        int t = wid;
        float a0 = 0.f, a1 = 0.f, a2 = 0.f, a3 = 0.f;
        for (int f = lane; f < F; f += 64) {
            float w0 = fc_node_w[t * 2 * F + f];
            float w1 = fc_node_w[t * 2 * F + F + f];
            a0 += w0 * attn_l[f];
            a1 += w1 * attn_l[F + f];
            a2 += w0 * attn_r[f];
            a3 += w1 * attn_r[F + f];
        }
        a0 = wave_reduce(a0); a1 = wave_reduce(a1);
        a2 = wave_reduce(a2); a3 = wave_reduce(a3);
        if (lane == 0) w_node[t] = make_float4(a0, a1, a2, a3);
    } else if (wid < 3 * F) {
        int t = wid - F;
        float a0 = 0.f, a1 = 0.f;
        for (int f = lane; f < F; f += 64) {
            a0 += fc_edge_w[t * 2 * F + f] * attn_e[f];
            a1 += fc_edge_w[t * 2 * F + F + f] * attn_e[F + f];
        }
        a0 = wave_reduce(a0); a1 = wave_reduce(a1);
        if (lane == 0) w_edge[t] = make_float2(a0, a1);
    } else if (wid < 3 * F + 6) {
        int j = wid - 3 * F;
        const float* b  = (j < 4) ? fc_node_b : fc_edge_b;
        const float* av = (j < 2) ? attn_l : (j < 4 ? attn_r : attn_e);
        int h = j & 1;
        float a0 = 0.f;
        for (int f = lane; f < F; f += 64)
            a0 += b[h * F + f] * av[h * F + f];
        a0 = wave_reduce(a0);
        if (lane == 0) bias[j] = a0;
    }
}

// K1: one wave per node: el/er (and zero the accumulator).
__global__ void node_kernel(const float* __restrict__ memory,
                            const float4* __restrict__ w_node,
                            const float* __restrict__ bias,
                            float4* __restrict__ el_er,
                            float4* __restrict__ node_acc, int N)
{
    int n    = blockIdx.x * (blockDim.x >> 6) + (threadIdx.x >> 6);
    int lane = threadIdx.x & 63;
    if (n >= N) return;
    const float* mrow = memory + (size_t)n * F;
    float a0 = 0.f, a1 = 0.f, a2 = 0.f, a3 = 0.f;
    for (int k = lane; k < F; k += 64) {
        float m  = mrow[k];
        float4 w = w_node[k];
        a0 += m * w.x; a1 += m * w.y; a2 += m * w.z; a3 += m * w.w;
    }
    a0 = wave_reduce(a0); a1 = wave_reduce(a1);
    a2 = wave_reduce(a2); a3 = wave_reduce(a3);
    if (lane == 0) {
        el_er[n]    = make_float4(a0 + bias[0], a1 + bias[1],
                                  a2 + bias[2], a3 + bias[3]);
        node_acc[n] = make_float4(0.f, 0.f, 0.f, 0.f);
    }
}

// K2: one wave per edge: ee + attention weight + atomic segment accumulate.
// Softmax is shift-invariant -> no segment_max pass needed (|e| <~ 12).
__global__ void edge_kernel(const float* __restrict__ edge_raw,
                            const float* __restrict__ edge_ts,
                            const float* __restrict__ node_ts,
                            const int* __restrict__ src,
                            const int* __restrict__ dst,
                            const float* __restrict__ time_w,
                            const float* __restrict__ time_b,
                            const float2* __restrict__ w_edge,
                            const float* __restrict__ bias,
                            const float4* __restrict__ el_er,
                            float* __restrict__ node_acc, int E)
{
    int e    = blockIdx.x * (blockDim.x >> 6) + (threadIdx.x >> 6);
    int lane = threadIdx.x & 63;
    if (e >= E) return;
    int s = src[e], d = dst[e];
    float td = edge_ts[e] - node_ts[s];
    const float* row = edge_raw + (size_t)e * F;
    float a0 = 0.f, a1 = 0.f;
    for (int k = lane; k < F; k += 64) {
        float r  = row[k];
        float2 w1 = w_edge[k];
        a0 += r * w1.x;
        a1 += r * w1.y;
        float c  = __cosf(fmaf(td, time_w[k], time_b[k]));
        float2 w2 = w_edge[F + k];
        a0 += c * w2.x;
        a1 += c * w2.y;
    }
    a0 = wave_reduce(a0);
    a1 = wave_reduce(a1);
    if (lane == 0) {
        float4 en_s = el_er[s];
        float4 en_d = el_er[d];
        float elp0 = en_s.x + a0 + bias[4];
        float elp1 = en_s.y + a1 + bias[5];
        float e0 = elp0 + en_d.z;
        float e1 = elp1 + en_d.w;
        e0 = e0 > 0.f ? e0 : NEG_SLOPE * e0;
        e1 = e1 > 0.f ? e1 : NEG_SLOPE * e1;
        float x0 = __expf(e0);
        float x1 = __expf(e1);
        float* acc = node_acc + (size_t)d * 4;
        atomicAdd(acc + 0, x0 * elp0);
        atomicAdd(acc + 1, x1 * elp1);
        atomicAdd(acc + 2, x0);
        atomicAdd(acc + 3, x1);
    }
}

// K3: out[n,f] = memory[n,f] + 0.5*(ft0 + ft1), ft = numer/denom (0 if empty).
__global__ void out_kernel(const float* __restrict__ memory,
                           const float4* __restrict__ node_acc,
                           float* __restrict__ out, int N)
{
    int i = blockIdx.x * blockDim.x + threadIdx.x;   // float2 index
    int total = N * (F / 2);
    if (i >= total) return;
    int n = i / (F / 2);
    float4 acc = node_acc[n];
    float ft0 = (acc.z != 0.f) ? acc.x / acc.z : 0.f;
    float ft1 = (acc.w != 0.f) ? acc.y / acc.w : 0.f;
    float add = 0.5f * (ft0 + ft1);
    float2 m = ((const float2*)memory)[i];
    float2 o;
    o.x = m.x + add;
    o.y = m.y + add;
    ((float2*)out)[i] = o;
}

extern "C" void kernel_launch(void* const* d_in, const int* in_sizes, int n_in,
                              void* d_out, int out_size, void* d_ws, size_t ws_size,
                              hipStream_t stream)
{
    const float* memory     = (const float*)d_in[0];
    const float* node_ts    = (const float*)d_in[1];
    const float* edge_raw   = (const float*)d_in[2];
    const float* edge_ts    = (const float*)d_in[3];
    const float* time_w     = (const float*)d_in[4];
    const float* time_b     = (const float*)d_in[5];
    const float* fc_node_w  = (const float*)d_in[6];
    const float* fc_node_b  = (const float*)d_in[7];
    const float* fc_edge_w  = (const float*)d_in[8];
    const float* fc_edge_b  = (const float*)d_in[9];
    const float* attn_l     = (const float*)d_in[10];
    const float* attn_r     = (const float*)d_in[11];
    const float* attn_e     = (const float*)d_in[12];
    const int*   src        = (const int*)d_in[13];
    const int*   dst        = (const int*)d_in[14];
    float*       out        = (float*)d_out;

    const int N = in_sizes[1];   // node_ts
    const int E = in_sizes[3];   // edge_ts

    // workspace layout (floats):
    // [0,400)        w_node   (100 x float4)
    // [400,800)      w_edge   (200 x float2)
    // [800,806)      bias     (pad to 816 for float4 alignment)
    // [816, 816+4N)  el_er    (N x float4)
    // [816+4N, 816+8N) node_acc (N x float4)
    float* ws = (float*)d_ws;
    float4* w_node   = (float4*)ws;
    float2* w_edge   = (float2*)(ws + 400);
    float*  bias     = ws + 800;
    float4* el_er    = (float4*)(ws + 816);
    float4* node_acc = (float4*)(ws + 816 + 4 * (size_t)N);

    {
        int waves  = 3 * F + 6;
        int blocks = (waves + 3) / 4;
        precompute_kernel<<<blocks, 256, 0, stream>>>(
            fc_node_w, fc_node_b, fc_edge_w, fc_edge_b,
            attn_l, attn_r, attn_e, w_node, w_edge, bias);
    }
    {
        int blocks = (N + 3) / 4;
        node_kernel<<<blocks, 256, 0, stream>>>(
            memory, w_node, bias, el_er, node_acc, N);
    }
    {
        int blocks = (E + 3) / 4;
        edge_kernel<<<blocks, 256, 0, stream>>>(
            edge_raw, edge_ts, node_ts, src, dst, time_w, time_b,
            w_edge, bias, el_er, (float*)node_acc, E);
    }
    {
        int total  = N * (F / 2);
        int blocks = (total + 255) / 256;
        out_kernel<<<blocks, 256, 0, stream>>>(memory, node_acc, out, N);
    }
}

// Round 2
// 665.012 us; speedup vs baseline: 1.1413x; 1.1413x over previous
//
#include <hip/hip_runtime.h>

// TemporalTransformerConv on MI355X.
// Algebraic collapse: node/edge GEMMs fold into attn vectors since the
// message value el_prime is scalar-per-head. Edge pass split into a
// streaming GEMV (LDS-tiled, coalesced float4) + a thread-per-edge atomic
// scatter so atomic-ack latency is amortized 64 edges/wave.

constexpr int F = 100;           // NODE_F == EDGE_F == TIME_D == OUT_F
constexpr float NEG_SLOPE = 0.2f;
constexpr int EPB = 32;          // edges per block in edge_gemv_kernel

__device__ __forceinline__ float wave_reduce(float v) {
#pragma unroll
    for (int off = 32; off > 0; off >>= 1)
        v += __shfl_down(v, off, 64);
    return v;
}

// K0: fold fc_* weights through attn vectors.
__global__ void precompute_kernel(
    const float* __restrict__ fc_node_w, const float* __restrict__ fc_node_b,
    const float* __restrict__ fc_edge_w, const float* __restrict__ fc_edge_b,
    const float* __restrict__ attn_l, const float* __restrict__ attn_r,
    const float* __restrict__ attn_e,
    float4* __restrict__ w_node, float2* __restrict__ w_edge,
    float* __restrict__ bias)
{
    int wid  = blockIdx.x * (blockDim.x >> 6) + (threadIdx.x >> 6);
    int lane = threadIdx.x & 63;
    if (wid < F) {
        int t = wid;
        float a0 = 0.f, a1 = 0.f, a2 = 0.f, a3 = 0.f;
        for (int f = lane; f < F; f += 64) {
            float w0 = fc_node_w[t * 2 * F + f];
            float w1 = fc_node_w[t * 2 * F + F + f];
            a0 += w0 * attn_l[f];
            a1 += w1 * attn_l[F + f];
            a2 += w0 * attn_r[f];
            a3 += w1 * attn_r[F + f];
        }
        a0 = wave_reduce(a0); a1 = wave_reduce(a1);
        a2 = wave_reduce(a2); a3 = wave_reduce(a3);
        if (lane == 0) w_node[t] = make_float4(a0, a1, a2, a3);
    } else if (wid < 3 * F) {
        int t = wid - F;
        float a0 = 0.f, a1 = 0.f;
        for (int f = lane; f < F; f += 64) {
            a0 += fc_edge_w[t * 2 * F + f] * attn_e[f];
            a1 += fc_edge_w[t * 2 * F + F + f] * attn_e[F + f];
        }
        a0 = wave_reduce(a0); a1 = wave_reduce(a1);
        if (lane == 0) w_edge[t] = make_float2(a0, a1);
    } else if (wid < 3 * F + 6) {
        int j = wid - 3 * F;
        const float* b  = (j < 4) ? fc_node_b : fc_edge_b;
        const float* av = (j < 2) ? attn_l : (j < 4 ? attn_r : attn_e);
        int h = j & 1;
        float a0 = 0.f;
        for (int f = lane; f < F; f += 64)
            a0 += b[h * F + f] * av[h * F + f];
        a0 = wave_reduce(a0);
        if (lane == 0) bias[j] = a0;
    }
}

// K1: one wave per node: el/er (and zero the accumulator).
__global__ void node_kernel(const float* __restrict__ memory,
                            const float4* __restrict__ w_node,
                            const float* __restrict__ bias,
                            float4* __restrict__ el_er,
                            float4* __restrict__ node_acc, int N)
{
    int n    = blockIdx.x * (blockDim.x >> 6) + (threadIdx.x >> 6);
    int lane = threadIdx.x & 63;
    if (n >= N) return;
    const float* mrow = memory + (size_t)n * F;
    float a0 = 0.f, a1 = 0.f, a2 = 0.f, a3 = 0.f;
    for (int k = lane; k < F; k += 64) {
        float m  = mrow[k];
        float4 w = w_node[k];
        a0 += m * w.x; a1 += m * w.y; a2 += m * w.z; a3 += m * w.w;
    }
    a0 = wave_reduce(a0); a1 = wave_reduce(a1);
    a2 = wave_reduce(a2); a3 = wave_reduce(a3);
    if (lane == 0) {
        el_er[n]    = make_float4(a0 + bias[0], a1 + bias[1],
                                  a2 + bias[2], a3 + bias[3]);
        node_acc[n] = make_float4(0.f, 0.f, 0.f, 0.f);
    }
}

// K2a: streaming edge GEMV. Block stages 32 edge rows in LDS (coalesced
// float4), 8 threads/edge reduce, group leader computes attention numer
// terms and writes float4 y = (x0*elp0, x1*elp1, x0, x1). No atomics here.
__global__ void edge_gemv_kernel(
    const float* __restrict__ edge_raw,
    const float* __restrict__ edge_ts,
    const float* __restrict__ node_ts,
    const int* __restrict__ src,
    const int* __restrict__ dst,
    const float* __restrict__ time_w,
    const float* __restrict__ time_b,
    const float2* __restrict__ w_edge,
    const float* __restrict__ bias,
    const float4* __restrict__ el_er,
    float4* __restrict__ edge_y, int E)
{
    __shared__ float  tile[EPB * F];     // 12.8 KB raw edge rows
    __shared__ float4 lw4[F];            // (we_raw0, we_raw1, we_te0, we_te1)
    __shared__ float2 lt2[F];            // (time_w, time_b)
    __shared__ float  td_s[EPB];
    __shared__ float2 el_s[EPB];         // el at src, both heads
    __shared__ float2 er_s[EPB];         // er at dst, both heads

    const int  t  = threadIdx.x;
    const long eb = (long)blockIdx.x * EPB;

    // ---- load phase (all coalesced / small) ----
    const float4* g4 = (const float4*)edge_raw;   // 25 float4 per row
    const long base4 = eb * 25;
    const long tot4  = (long)E * 25;
#pragma unroll
    for (int r = 0; r < 4; ++r) {
        int idx = t + r * 256;
        if (idx < EPB * 25 && base4 + idx < tot4)
            ((float4*)tile)[idx] = g4[base4 + idx];
    }
    if (t < F) {
        float2 wr = w_edge[t];
        float2 wt = w_edge[F + t];
        lw4[t] = make_float4(wr.x, wr.y, wt.x, wt.y);
        lt2[t] = make_float2(time_w[t], time_b[t]);
    }
    if (t < EPB) {
        long e = eb + t;
        if (e < E) {
            int s = src[e], d = dst[e];
            td_s[t] = edge_ts[e] - node_ts[s];
            float4 a = el_er[s];
            float4 b = el_er[d];
            el_s[t] = make_float2(a.x, a.y);
            er_s[t] = make_float2(b.z, b.w);
        }
    }
    __syncthreads();

    // ---- compute phase: 8 threads per edge ----
    const int el_ = t >> 3;      // local edge 0..31
    const int s8  = t & 7;       // slot within edge
    const float td = td_s[el_];
    float a0 = 0.f, a1 = 0.f;
#pragma unroll
    for (int i = 0; i < 13; ++i) {
        int k = s8 + 8 * i;
        if (k < F) {
            float  r  = tile[el_ * F + k];
            float4 w  = lw4[k];
            float2 tm = lt2[k];
            float  c  = __cosf(fmaf(td, tm.x, tm.y));
            a0 = fmaf(r, w.x, fmaf(c, w.z, a0));
            a1 = fmaf(r, w.y, fmaf(c, w.w, a1));
        }
    }
    // reduce within the 8-lane group (contiguous lanes)
    a0 += __shfl_down(a0, 4, 64);  a1 += __shfl_down(a1, 4, 64);
    a0 += __shfl_down(a0, 2, 64);  a1 += __shfl_down(a1, 2, 64);
    a0 += __shfl_down(a0, 1, 64);  a1 += __shfl_down(a1, 1, 64);

    if (s8 == 0) {
        long e = eb + el_;
        if (e < E) {
            float elp0 = el_s[el_].x + a0 + bias[4];
            float elp1 = el_s[el_].y + a1 + bias[5];
            float e0 = elp0 + er_s[el_].x;
            float e1 = elp1 + er_s[el_].y;
            e0 = e0 > 0.f ? e0 : NEG_SLOPE * e0;
            e1 = e1 > 0.f ? e1 : NEG_SLOPE * e1;
            float x0 = __expf(e0);
            float x1 = __expf(e1);
            edge_y[e] = make_float4(x0 * elp0, x1 * elp1, x0, x1);
        }
    }
}

// K2b: thread-per-edge atomic scatter. One wave issues 256 fire-and-forget
// atomics and drains once -> atomic ack latency amortized over 64 edges.
__global__ void scatter_kernel(const float4* __restrict__ edge_y,
                               const int* __restrict__ dst,
                               float* __restrict__ node_acc, int E)
{
    int i = blockIdx.x * blockDim.x + threadIdx.x;
    if (i >= E) return;
    float4 y = edge_y[i];
    int d = dst[i];
    float* acc = node_acc + (size_t)d * 4;
    atomicAdd(acc + 0, y.x);
    atomicAdd(acc + 1, y.y);
    atomicAdd(acc + 2, y.z);
    atomicAdd(acc + 3, y.w);
}

// K3: out[n,f] = memory[n,f] + 0.5*(ft0 + ft1), ft = numer/denom (0 if empty).
__global__ void out_kernel(const float* __restrict__ memory,
                           const float4* __restrict__ node_acc,
                           float* __restrict__ out, int N)
{
    int i = blockIdx.x * blockDim.x + threadIdx.x;   // float2 index
    int total = N * (F / 2);
    if (i >= total) return;
    int n = i / (F / 2);
    float4 acc = node_acc[n];
    float ft0 = (acc.z != 0.f) ? acc.x / acc.z : 0.f;
    float ft1 = (acc.w != 0.f) ? acc.y / acc.w : 0.f;
    float add = 0.5f * (ft0 + ft1);
    float2 m = ((const float2*)memory)[i];
    float2 o;
    o.x = m.x + add;
    o.y = m.y + add;
    ((float2*)out)[i] = o;
}

extern "C" void kernel_launch(void* const* d_in, const int* in_sizes, int n_in,
                              void* d_out, int out_size, void* d_ws, size_t ws_size,
                              hipStream_t stream)
{
    const float* memory     = (const float*)d_in[0];
    const float* node_ts    = (const float*)d_in[1];
    const float* edge_raw   = (const float*)d_in[2];
    const float* edge_ts    = (const float*)d_in[3];
    const float* time_w     = (const float*)d_in[4];
    const float* time_b     = (const float*)d_in[5];
    const float* fc_node_w  = (const float*)d_in[6];
    const float* fc_node_b  = (const float*)d_in[7];
    const float* fc_edge_w  = (const float*)d_in[8];
    const float* fc_edge_b  = (const float*)d_in[9];
    const float* attn_l     = (const float*)d_in[10];
    const float* attn_r     = (const float*)d_in[11];
    const float* attn_e     = (const float*)d_in[12];
    const int*   src        = (const int*)d_in[13];
    const int*   dst        = (const int*)d_in[14];
    float*       out        = (float*)d_out;

    const int N = in_sizes[1];   // node_ts
    const int E = in_sizes[3];   // edge_ts

    // workspace layout (floats):
    // [0,400)              w_node   (100 x float4)
    // [400,800)            w_edge   (200 x float2)
    // [800,816)            bias (6 used, padded to float4 alignment)
    // [816, 816+4N)        el_er    (N x float4)
    // [816+4N, 816+8N)     node_acc (N x float4)
    // [816+8N, 816+8N+4E)  edge_y   (E x float4)
    float* ws = (float*)d_ws;
    float4* w_node   = (float4*)ws;
    float2* w_edge   = (float2*)(ws + 400);
    float*  bias     = ws + 800;
    float4* el_er    = (float4*)(ws + 816);
    float4* node_acc = (float4*)(ws + 816 + 4 * (size_t)N);
    float4* edge_y   = (float4*)(ws + 816 + 8 * (size_t)N);

    {
        int waves  = 3 * F + 6;
        int blocks = (waves + 3) / 4;
        precompute_kernel<<<blocks, 256, 0, stream>>>(
            fc_node_w, fc_node_b, fc_edge_w, fc_edge_b,
            attn_l, attn_r, attn_e, w_node, w_edge, bias);
    }
    {
        int blocks = (N + 3) / 4;
        node_kernel<<<blocks, 256, 0, stream>>>(
            memory, w_node, bias, el_er, node_acc, N);
    }
    {
        int blocks = (E + EPB - 1) / EPB;
        edge_gemv_kernel<<<blocks, 256, 0, stream>>>(
            edge_raw, edge_ts, node_ts, src, dst, time_w, time_b,
            w_edge, bias, el_er, edge_y, E);
    }
    {
        int blocks = (E + 255) / 256;
        scatter_kernel<<<blocks, 256, 0, stream>>>(
            edge_y, dst, (float*)node_acc, E);
    }
    {
        int total  = N * (F / 2);
        int blocks = (total + 255) / 256;
        out_kernel<<<blocks, 256, 0, stream>>>(memory, node_acc, out, N);
    }
}

// Round 3
// 650.478 us; speedup vs baseline: 1.1668x; 1.0223x over previous
//
#include <hip/hip_runtime.h>

// TemporalTransformerConv on MI355X.
// Algebraic collapse: node/edge GEMMs fold into attn vectors since the
// message value el_prime is scalar-per-head. Edge pass = streaming GEMV
// (direct global float4 reads, SoA weights in LDS) + thread-per-edge
// atomic scatter into 8 replica tables (contention 16-way -> ~2-way).
// NOTE: harness re-poison of the 1.28 GB ws (~194 us fill) + input restore
// are fixed per-iteration overhead on the timed stream (~300 us floor).

constexpr int F = 100;           // NODE_F == EDGE_F == TIME_D == OUT_F
constexpr float NEG_SLOPE = 0.2f;
constexpr int EPB = 32;          // edges per block in edge_gemv_kernel
constexpr int NREP = 8;          // accumulator replicas

__device__ __forceinline__ float wave_reduce(float v) {
#pragma unroll
    for (int off = 32; off > 0; off >>= 1)
        v += __shfl_down(v, off, 64);
    return v;
}

// K0: fold fc_* weights through attn vectors.
__global__ void precompute_kernel(
    const float* __restrict__ fc_node_w, const float* __restrict__ fc_node_b,
    const float* __restrict__ fc_edge_w, const float* __restrict__ fc_edge_b,
    const float* __restrict__ attn_l, const float* __restrict__ attn_r,
    const float* __restrict__ attn_e,
    float4* __restrict__ w_node, float2* __restrict__ w_edge,
    float* __restrict__ bias)
{
    int wid  = blockIdx.x * (blockDim.x >> 6) + (threadIdx.x >> 6);
    int lane = threadIdx.x & 63;
    if (wid < F) {
        int t = wid;
        float a0 = 0.f, a1 = 0.f, a2 = 0.f, a3 = 0.f;
        for (int f = lane; f < F; f += 64) {
            float w0 = fc_node_w[t * 2 * F + f];
            float w1 = fc_node_w[t * 2 * F + F + f];
            a0 += w0 * attn_l[f];
            a1 += w1 * attn_l[F + f];
            a2 += w0 * attn_r[f];
            a3 += w1 * attn_r[F + f];
        }
        a0 = wave_reduce(a0); a1 = wave_reduce(a1);
        a2 = wave_reduce(a2); a3 = wave_reduce(a3);
        if (lane == 0) w_node[t] = make_float4(a0, a1, a2, a3);
    } else if (wid < 3 * F) {
        int t = wid - F;
        float a0 = 0.f, a1 = 0.f;
        for (int f = lane; f < F; f += 64) {
            a0 += fc_edge_w[t * 2 * F + f] * attn_e[f];
            a1 += fc_edge_w[t * 2 * F + F + f] * attn_e[F + f];
        }
        a0 = wave_reduce(a0); a1 = wave_reduce(a1);
        if (lane == 0) w_edge[t] = make_float2(a0, a1);
    } else if (wid < 3 * F + 6) {
        int j = wid - 3 * F;
        const float* b  = (j < 4) ? fc_node_b : fc_edge_b;
        const float* av = (j < 2) ? attn_l : (j < 4 ? attn_r : attn_e);
        int h = j & 1;
        float a0 = 0.f;
        for (int f = lane; f < F; f += 64)
            a0 += b[h * F + f] * av[h * F + f];
        a0 = wave_reduce(a0);
        if (lane == 0) bias[j] = a0;
    }
}

// K1: one wave per node: el/er.
__global__ void node_kernel(const float* __restrict__ memory,
                            const float4* __restrict__ w_node,
                            const float* __restrict__ bias,
                            float4* __restrict__ el_er, int N)
{
    int n    = blockIdx.x * (blockDim.x >> 6) + (threadIdx.x >> 6);
    int lane = threadIdx.x & 63;
    if (n >= N) return;
    const float* mrow = memory + (size_t)n * F;
    float a0 = 0.f, a1 = 0.f, a2 = 0.f, a3 = 0.f;
    for (int k = lane; k < F; k += 64) {
        float m  = mrow[k];
        float4 w = w_node[k];
        a0 += m * w.x; a1 += m * w.y; a2 += m * w.z; a3 += m * w.w;
    }
    a0 = wave_reduce(a0); a1 = wave_reduce(a1);
    a2 = wave_reduce(a2); a3 = wave_reduce(a3);
    if (lane == 0)
        el_er[n] = make_float4(a0 + bias[0], a1 + bias[1],
                               a2 + bias[2], a3 + bias[3]);
}

// K1b: zero the replica accumulators (NREP * N float4).
__global__ void zero_kernel(float4* __restrict__ acc, int n4)
{
    int i = blockIdx.x * blockDim.x + threadIdx.x;
    if (i < n4) acc[i] = make_float4(0.f, 0.f, 0.f, 0.f);
}

// K2a: streaming edge GEMV. Edge rows read directly from HBM as float4
// (8 threads/edge, 8x128B segments per wave, fully used). Weights in LDS
// as 6 SoA float4[25] arrays (broadcast reads). Writes one float4 per edge
// y = (x0*elp0, x1*elp1, x0, x1). No atomics here.
__global__ void edge_gemv_kernel(
    const float* __restrict__ edge_raw,
    const float* __restrict__ edge_ts,
    const float* __restrict__ node_ts,
    const int* __restrict__ src,
    const int* __restrict__ dst,
    const float* __restrict__ time_w,
    const float* __restrict__ time_b,
    const float2* __restrict__ w_edge,
    const float* __restrict__ bias,
    const float4* __restrict__ el_er,
    float4* __restrict__ edge_y, int E)
{
    __shared__ float4 wx4[25], wy4[25], wz4[25], ww4[25], tw4[25], tb4[25];
    __shared__ float  td_s[EPB];
    __shared__ float2 el_s[EPB];
    __shared__ float2 er_s[EPB];

    const int  t  = threadIdx.x;
    const long eb = (long)blockIdx.x * EPB;

    if (t < 25) {
        float4 x, y, z, w, tw, tb;
#pragma unroll
        for (int j = 0; j < 4; ++j) {
            int k = 4 * t + j;
            float2 wr = w_edge[k];
            float2 wt = w_edge[F + k];
            ((float*)&x)[j]  = wr.x;  ((float*)&y)[j]  = wr.y;
            ((float*)&z)[j]  = wt.x;  ((float*)&w)[j]  = wt.y;
            ((float*)&tw)[j] = time_w[k];
            ((float*)&tb)[j] = time_b[k];
        }
        wx4[t] = x; wy4[t] = y; wz4[t] = z; ww4[t] = w;
        tw4[t] = tw; tb4[t] = tb;
    } else if (t >= 64 && t < 64 + EPB) {
        int  l = t - 64;
        long e = eb + l;
        if (e < E) {
            int s = src[e], d = dst[e];
            td_s[l] = edge_ts[e] - node_ts[s];
            float4 a = el_er[s];
            float4 b = el_er[d];
            el_s[l] = make_float2(a.x, a.y);
            er_s[l] = make_float2(b.z, b.w);
        }
    }
    __syncthreads();

    const int  el_ = t >> 3;      // local edge 0..31
    const int  s8  = t & 7;       // slot within edge
    const long e   = eb + el_;
    float a0 = 0.f, a1 = 0.f;
    if (e < E) {
        const float  td   = td_s[el_];
        const float4* row = (const float4*)edge_raw + e * 25;
#pragma unroll
        for (int i = 0; i < 4; ++i) {
            int c = s8 + 8 * i;
            if (c < 25) {
                float4 r  = row[c];
                float4 x  = wx4[c], y = wy4[c], z = wz4[c], w = ww4[c];
                float4 tw = tw4[c], tb = tb4[c];
                float c0 = __cosf(fmaf(td, tw.x, tb.x));
                float c1 = __cosf(fmaf(td, tw.y, tb.y));
                float c2 = __cosf(fmaf(td, tw.z, tb.z));
                float c3 = __cosf(fmaf(td, tw.w, tb.w));
                a0 = fmaf(r.x, x.x, fmaf(c0, z.x, a0));
                a1 = fmaf(r.x, y.x, fmaf(c0, w.x, a1));
                a0 = fmaf(r.y, x.y, fmaf(c1, z.y, a0));
                a1 = fmaf(r.y, y.y, fmaf(c1, w.y, a1));
                a0 = fmaf(r.z, x.z, fmaf(c2, z.z, a0));
                a1 = fmaf(r.z, y.z, fmaf(c2, w.z, a1));
                a0 = fmaf(r.w, x.w, fmaf(c3, z.w, a0));
                a1 = fmaf(r.w, y.w, fmaf(c3, w.w, a1));
            }
        }
    }
    a0 += __shfl_down(a0, 4, 64);  a1 += __shfl_down(a1, 4, 64);
    a0 += __shfl_down(a0, 2, 64);  a1 += __shfl_down(a1, 2, 64);
    a0 += __shfl_down(a0, 1, 64);  a1 += __shfl_down(a1, 1, 64);

    if (s8 == 0 && e < E) {
        float elp0 = el_s[el_].x + a0 + bias[4];
        float elp1 = el_s[el_].y + a1 + bias[5];
        float e0 = elp0 + er_s[el_].x;
        float e1 = elp1 + er_s[el_].y;
        e0 = e0 > 0.f ? e0 : NEG_SLOPE * e0;
        e1 = e1 > 0.f ? e1 : NEG_SLOPE * e1;
        float x0 = __expf(e0);
        float x1 = __expf(e1);
        edge_y[e] = make_float4(x0 * elp0, x1 * elp1, x0, x1);
    }
}

// K2b: thread-per-edge atomic scatter into NREP replica tables.
// replica = lane&7 spreads same-dst collisions across tables.
__global__ void scatter_kernel(const float4* __restrict__ edge_y,
                               const int* __restrict__ dst,
                               float* __restrict__ acc, int E, int N)
{
    int i = blockIdx.x * blockDim.x + threadIdx.x;
    if (i >= E) return;
    float4 y = edge_y[i];
    int d = dst[i];
    int r = threadIdx.x & (NREP - 1);
    float* a = acc + ((size_t)r * N + d) * 4;
    atomicAdd(a + 0, y.x);
    atomicAdd(a + 1, y.y);
    atomicAdd(a + 2, y.z);
    atomicAdd(a + 3, y.w);
}

// K2c: sum replicas, compute per-node additive term.
__global__ void finalize_kernel(const float4* __restrict__ acc,
                                float* __restrict__ addbuf, int N)
{
    int n = blockIdx.x * blockDim.x + threadIdx.x;
    if (n >= N) return;
    float s0 = 0.f, s1 = 0.f, s2 = 0.f, s3 = 0.f;
#pragma unroll
    for (int r = 0; r < NREP; ++r) {
        float4 v = acc[(size_t)r * N + n];
        s0 += v.x; s1 += v.y; s2 += v.z; s3 += v.w;
    }
    float ft0 = (s2 != 0.f) ? s0 / s2 : 0.f;
    float ft1 = (s3 != 0.f) ? s1 / s3 : 0.f;
    addbuf[n] = 0.5f * (ft0 + ft1);
}

// K3: out[n,f] = memory[n,f] + addbuf[n].
__global__ void out_kernel(const float* __restrict__ memory,
                           const float* __restrict__ addbuf,
                           float* __restrict__ out, int N)
{
    int i = blockIdx.x * blockDim.x + threadIdx.x;   // float2 index
    int total = N * (F / 2);
    if (i >= total) return;
    int n = i / (F / 2);
    float add = addbuf[n];
    float2 m = ((const float2*)memory)[i];
    float2 o;
    o.x = m.x + add;
    o.y = m.y + add;
    ((float2*)out)[i] = o;
}

extern "C" void kernel_launch(void* const* d_in, const int* in_sizes, int n_in,
                              void* d_out, int out_size, void* d_ws, size_t ws_size,
                              hipStream_t stream)
{
    const float* memory     = (const float*)d_in[0];
    const float* node_ts    = (const float*)d_in[1];
    const float* edge_raw   = (const float*)d_in[2];
    const float* edge_ts    = (const float*)d_in[3];
    const float* time_w     = (const float*)d_in[4];
    const float* time_b     = (const float*)d_in[5];
    const float* fc_node_w  = (const float*)d_in[6];
    const float* fc_node_b  = (const float*)d_in[7];
    const float* fc_edge_w  = (const float*)d_in[8];
    const float* fc_edge_b  = (const float*)d_in[9];
    const float* attn_l     = (const float*)d_in[10];
    const float* attn_r     = (const float*)d_in[11];
    const float* attn_e     = (const float*)d_in[12];
    const int*   src        = (const int*)d_in[13];
    const int*   dst        = (const int*)d_in[14];
    float*       out        = (float*)d_out;

    const int N = in_sizes[1];   // node_ts
    const int E = in_sizes[3];   // edge_ts

    // workspace layout (floats):
    // [0,400)                    w_node   (100 x float4)
    // [400,800)                  w_edge   (200 x float2)
    // [800,816)                  bias (6 used, padded)
    // [816, +4N)                 el_er    (N x float4)
    // [816+4N, +32N)             acc      (NREP x N x float4)
    // [816+36N, +N)              addbuf   (N floats)
    // [816+37N, +4E)             edge_y   (E x float4)
    float* ws = (float*)d_ws;
    float4* w_node  = (float4*)ws;
    float2* w_edge  = (float2*)(ws + 400);
    float*  bias    = ws + 800;
    float4* el_er   = (float4*)(ws + 816);
    float4* acc     = (float4*)(ws + 816 + 4 * (size_t)N);
    float*  addbuf  = ws + 816 + 36 * (size_t)N;
    float4* edge_y  = (float4*)(ws + 816 + 37 * (size_t)N);

    {
        int waves  = 3 * F + 6;
        int blocks = (waves + 3) / 4;
        precompute_kernel<<<blocks, 256, 0, stream>>>(
            fc_node_w, fc_node_b, fc_edge_w, fc_edge_b,
            attn_l, attn_r, attn_e, w_node, w_edge, bias);
    }
    {
        int blocks = (N + 3) / 4;
        node_kernel<<<blocks, 256, 0, stream>>>(
            memory, w_node, bias, el_er, N);
    }
    {
        int n4     = NREP * N;
        int blocks = (n4 + 255) / 256;
        zero_kernel<<<blocks, 256, 0, stream>>>(acc, n4);
    }
    {
        int blocks = (E + EPB - 1) / EPB;
        edge_gemv_kernel<<<blocks, 256, 0, stream>>>(
            edge_raw, edge_ts, node_ts, src, dst, time_w, time_b,
            w_edge, bias, el_er, edge_y, E);
    }
    {
        int blocks = (E + 255) / 256;
        scatter_kernel<<<blocks, 256, 0, stream>>>(
            edge_y, dst, (float*)acc, E, N);
    }
    {
        int blocks = (N + 255) / 256;
        finalize_kernel<<<blocks, 256, 0, stream>>>(acc, addbuf, N);
    }
    {
        int total  = N * (F / 2);
        int blocks = (total + 255) / 256;
        out_kernel<<<blocks, 256, 0, stream>>>(memory, addbuf, out, N);
    }
}

// Round 4
// 550.951 us; speedup vs baseline: 1.3776x; 1.1806x over previous
//
#include <hip/hip_runtime.h>

// TemporalTransformerConv on MI355X.
// Algebraic collapse: node/edge GEMMs fold into attn vectors since the
// message value el_prime is scalar-per-head. Edge aggregation via on-the-fly
// CSR bucketing (int cursor atomics + plain float4 stores) instead of fp32
// atomics: 12.8M memory-side f32 RMWs -> 1.6M int atomics. R3 showed replica
// spreading didn't help => atomics were rate-bound, not contention-bound.
// Fixed per-iter harness overhead (1.28 GB ws poison ~194us + input restore)
// is untouchable.

constexpr int F = 100;           // NODE_F == EDGE_F == TIME_D == OUT_F
constexpr float NEG_SLOPE = 0.2f;
constexpr int EPB = 32;          // edges per block in edge_gemv_kernel

__device__ __forceinline__ float wave_reduce(float v) {
#pragma unroll
    for (int off = 32; off > 0; off >>= 1)
        v += __shfl_down(v, off, 64);
    return v;
}

// K0: fold fc_* weights through attn vectors.
__global__ void precompute_kernel(
    const float* __restrict__ fc_node_w, const float* __restrict__ fc_node_b,
    const float* __restrict__ fc_edge_w, const float* __restrict__ fc_edge_b,
    const float* __restrict__ attn_l, const float* __restrict__ attn_r,
    const float* __restrict__ attn_e,
    float4* __restrict__ w_node, float2* __restrict__ w_edge,
    float* __restrict__ bias)
{
    int wid  = blockIdx.x * (blockDim.x >> 6) + (threadIdx.x >> 6);
    int lane = threadIdx.x & 63;
    if (wid < F) {
        int t = wid;
        float a0 = 0.f, a1 = 0.f, a2 = 0.f, a3 = 0.f;
        for (int f = lane; f < F; f += 64) {
            float w0 = fc_node_w[t * 2 * F + f];
            float w1 = fc_node_w[t * 2 * F + F + f];
            a0 += w0 * attn_l[f];
            a1 += w1 * attn_l[F + f];
            a2 += w0 * attn_r[f];
            a3 += w1 * attn_r[F + f];
        }
        a0 = wave_reduce(a0); a1 = wave_reduce(a1);
        a2 = wave_reduce(a2); a3 = wave_reduce(a3);
        if (lane == 0) w_node[t] = make_float4(a0, a1, a2, a3);
    } else if (wid < 3 * F) {
        int t = wid - F;
        float a0 = 0.f, a1 = 0.f;
        for (int f = lane; f < F; f += 64) {
            a0 += fc_edge_w[t * 2 * F + f] * attn_e[f];
            a1 += fc_edge_w[t * 2 * F + F + f] * attn_e[F + f];
        }
        a0 = wave_reduce(a0); a1 = wave_reduce(a1);
        if (lane == 0) w_edge[t] = make_float2(a0, a1);
    } else if (wid < 3 * F + 6) {
        int j = wid - 3 * F;
        const float* b  = (j < 4) ? fc_node_b : fc_edge_b;
        const float* av = (j < 2) ? attn_l : (j < 4 ? attn_r : attn_e);
        int h = j & 1;
        float a0 = 0.f;
        for (int f = lane; f < F; f += 64)
            a0 += b[h * F + f] * av[h * F + f];
        a0 = wave_reduce(a0);
        if (lane == 0) bias[j] = a0;
    }
}

// K1: one wave per node: el/er. Also zeros cnt[n] for the CSR build.
__global__ void node_kernel(const float* __restrict__ memory,
                            const float4* __restrict__ w_node,
                            const float* __restrict__ bias,
                            float4* __restrict__ el_er,
                            int* __restrict__ cnt, int N)
{
    int n    = blockIdx.x * (blockDim.x >> 6) + (threadIdx.x >> 6);
    int lane = threadIdx.x & 63;
    if (n >= N) return;
    const float* mrow = memory + (size_t)n * F;
    float a0 = 0.f, a1 = 0.f, a2 = 0.f, a3 = 0.f;
    for (int k = lane; k < F; k += 64) {
        float m  = mrow[k];
        float4 w = w_node[k];
        a0 += m * w.x; a1 += m * w.y; a2 += m * w.z; a3 += m * w.w;
    }
    a0 = wave_reduce(a0); a1 = wave_reduce(a1);
    a2 = wave_reduce(a2); a3 = wave_reduce(a3);
    if (lane == 0)
        el_er[n] = make_float4(a0 + bias[0], a1 + bias[1],
                               a2 + bias[2], a3 + bias[3]);
    if (lane == 1)
        cnt[n] = 0;
}

// CSR step 1: in-degree histogram.
__global__ void count_kernel(const int* __restrict__ dst,
                             int* __restrict__ cnt, int E)
{
    int i = blockIdx.x * blockDim.x + threadIdx.x;
    if (i < E) atomicAdd(&cnt[dst[i]], 1);
}

// CSR step 2a: per-block exclusive scan (Hillis-Steele in LDS).
__global__ void scan1_kernel(const int* __restrict__ cnt,
                             int* __restrict__ offs,
                             int* __restrict__ bsum, int N)
{
    __shared__ int tmp[256];
    int i = blockIdx.x * 256 + threadIdx.x;
    int v = (i < N) ? cnt[i] : 0;
    tmp[threadIdx.x] = v;
    __syncthreads();
    for (int d = 1; d < 256; d <<= 1) {
        int t = (threadIdx.x >= d) ? tmp[threadIdx.x - d] : 0;
        __syncthreads();
        tmp[threadIdx.x] += t;
        __syncthreads();
    }
    if (i < N) offs[i] = tmp[threadIdx.x] - v;    // exclusive
    if (threadIdx.x == 255) bsum[blockIdx.x] = tmp[255];
}

// CSR step 2b: scan the block sums (nb <= 256) -> exclusive block offsets.
__global__ void scan2_kernel(int* __restrict__ bsum, int nb)
{
    __shared__ int tmp[256];
    int v = (threadIdx.x < nb) ? bsum[threadIdx.x] : 0;
    tmp[threadIdx.x] = v;
    __syncthreads();
    for (int d = 1; d < 256; d <<= 1) {
        int t = (threadIdx.x >= d) ? tmp[threadIdx.x - d] : 0;
        __syncthreads();
        tmp[threadIdx.x] += t;
        __syncthreads();
    }
    if (threadIdx.x < nb) bsum[threadIdx.x] = tmp[threadIdx.x] - v;
}

// CSR step 2c: add block offsets; init cursor = offs.
__global__ void scan3_kernel(int* __restrict__ offs,
                             const int* __restrict__ bsum,
                             int* __restrict__ cursor, int N)
{
    int i = blockIdx.x * 256 + threadIdx.x;
    if (i < N) {
        int o = offs[i] + bsum[blockIdx.x];
        offs[i]   = o;
        cursor[i] = o;
    }
}

// K2: streaming edge GEMV. Edge rows read directly from HBM as float4
// (8 threads/edge). Weights in LDS as SoA float4[25] (broadcast reads).
// Leader computes y = (x0*elp0, x1*elp1, x0, x1) and bucket-writes it at
// pos = cursor[dst]++ (one int atomic per edge, plain float4 store).
__global__ void edge_gemv_kernel(
    const float* __restrict__ edge_raw,
    const float* __restrict__ edge_ts,
    const float* __restrict__ node_ts,
    const int* __restrict__ src,
    const int* __restrict__ dst,
    const float* __restrict__ time_w,
    const float* __restrict__ time_b,
    const float2* __restrict__ w_edge,
    const float* __restrict__ bias,
    const float4* __restrict__ el_er,
    int* __restrict__ cursor,
    float4* __restrict__ bucket, int E)
{
    __shared__ float4 wx4[25], wy4[25], wz4[25], ww4[25], tw4[25], tb4[25];
    __shared__ float  td_s[EPB];
    __shared__ float2 el_s[EPB];
    __shared__ float2 er_s[EPB];
    __shared__ int    d_s[EPB];

    const int  t  = threadIdx.x;
    const long eb = (long)blockIdx.x * EPB;

    if (t < 25) {
        float4 x, y, z, w, tw, tb;
#pragma unroll
        for (int j = 0; j < 4; ++j) {
            int k = 4 * t + j;
            float2 wr = w_edge[k];
            float2 wt = w_edge[F + k];
            ((float*)&x)[j]  = wr.x;  ((float*)&y)[j]  = wr.y;
            ((float*)&z)[j]  = wt.x;  ((float*)&w)[j]  = wt.y;
            ((float*)&tw)[j] = time_w[k];
            ((float*)&tb)[j] = time_b[k];
        }
        wx4[t] = x; wy4[t] = y; wz4[t] = z; ww4[t] = w;
        tw4[t] = tw; tb4[t] = tb;
    } else if (t >= 64 && t < 64 + EPB) {
        int  l = t - 64;
        long e = eb + l;
        if (e < E) {
            int s = src[e], d = dst[e];
            d_s[l]  = d;
            td_s[l] = edge_ts[e] - node_ts[s];
            float4 a = el_er[s];
            float4 b = el_er[d];
            el_s[l] = make_float2(a.x, a.y);
            er_s[l] = make_float2(b.z, b.w);
        }
    }
    __syncthreads();

    const int  el_ = t >> 3;      // local edge 0..31
    const int  s8  = t & 7;       // slot within edge
    const long e   = eb + el_;
    float a0 = 0.f, a1 = 0.f;
    if (e < E) {
        const float  td   = td_s[el_];
        const float4* row = (const float4*)edge_raw + e * 25;
#pragma unroll
        for (int i = 0; i < 4; ++i) {
            int c = s8 + 8 * i;
            if (c < 25) {
                float4 r  = row[c];
                float4 x  = wx4[c], y = wy4[c], z = wz4[c], w = ww4[c];
                float4 tw = tw4[c], tb = tb4[c];
                float c0 = __cosf(fmaf(td, tw.x, tb.x));
                float c1 = __cosf(fmaf(td, tw.y, tb.y));
                float c2 = __cosf(fmaf(td, tw.z, tb.z));
                float c3 = __cosf(fmaf(td, tw.w, tb.w));
                a0 = fmaf(r.x, x.x, fmaf(c0, z.x, a0));
                a1 = fmaf(r.x, y.x, fmaf(c0, w.x, a1));
                a0 = fmaf(r.y, x.y, fmaf(c1, z.y, a0));
                a1 = fmaf(r.y, y.y, fmaf(c1, w.y, a1));
                a0 = fmaf(r.z, x.z, fmaf(c2, z.z, a0));
                a1 = fmaf(r.z, y.z, fmaf(c2, w.z, a1));
                a0 = fmaf(r.w, x.w, fmaf(c3, z.w, a0));
                a1 = fmaf(r.w, y.w, fmaf(c3, w.w, a1));
            }
        }
    }
    a0 += __shfl_down(a0, 4, 64);  a1 += __shfl_down(a1, 4, 64);
    a0 += __shfl_down(a0, 2, 64);  a1 += __shfl_down(a1, 2, 64);
    a0 += __shfl_down(a0, 1, 64);  a1 += __shfl_down(a1, 1, 64);

    if (s8 == 0 && e < E) {
        float elp0 = el_s[el_].x + a0 + bias[4];
        float elp1 = el_s[el_].y + a1 + bias[5];
        float e0 = elp0 + er_s[el_].x;
        float e1 = elp1 + er_s[el_].y;
        e0 = e0 > 0.f ? e0 : NEG_SLOPE * e0;
        e1 = e1 > 0.f ? e1 : NEG_SLOPE * e1;
        float x0 = __expf(e0);
        float x1 = __expf(e1);
        int pos = atomicAdd(&cursor[d_s[el_]], 1);
        bucket[pos] = make_float4(x0 * elp0, x1 * elp1, x0, x1);
    }
}

// K3a: per-node bucket reduce (16 lanes per node; bucket is read in
// globally-sequential order -> coalesced). No atomics.
__global__ void reduce_kernel(const float4* __restrict__ bucket,
                              const int* __restrict__ offs,
                              const int* __restrict__ cnt,
                              float* __restrict__ addbuf, int N)
{
    int g = blockIdx.x * (blockDim.x >> 4) + (threadIdx.x >> 4);  // node
    int l = threadIdx.x & 15;
    if (g >= N) return;
    int base = offs[g];
    int deg  = cnt[g];
    float s0 = 0.f, s1 = 0.f, s2 = 0.f, s3 = 0.f;
    for (int j = l; j < deg; j += 16) {
        float4 v = bucket[base + j];
        s0 += v.x; s1 += v.y; s2 += v.z; s3 += v.w;
    }
    s0 += __shfl_down(s0, 8, 64); s1 += __shfl_down(s1, 8, 64);
    s2 += __shfl_down(s2, 8, 64); s3 += __shfl_down(s3, 8, 64);
    s0 += __shfl_down(s0, 4, 64); s1 += __shfl_down(s1, 4, 64);
    s2 += __shfl_down(s2, 4, 64); s3 += __shfl_down(s3, 4, 64);
    s0 += __shfl_down(s0, 2, 64); s1 += __shfl_down(s1, 2, 64);
    s2 += __shfl_down(s2, 2, 64); s3 += __shfl_down(s3, 2, 64);
    s0 += __shfl_down(s0, 1, 64); s1 += __shfl_down(s1, 1, 64);
    s2 += __shfl_down(s2, 1, 64); s3 += __shfl_down(s3, 1, 64);
    if (l == 0) {
        float ft0 = (s2 != 0.f) ? s0 / s2 : 0.f;
        float ft1 = (s3 != 0.f) ? s1 / s3 : 0.f;
        addbuf[g] = 0.5f * (ft0 + ft1);
    }
}

// K3b: out[n,f] = memory[n,f] + addbuf[n].
__global__ void out_kernel(const float* __restrict__ memory,
                           const float* __restrict__ addbuf,
                           float* __restrict__ out, int N)
{
    int i = blockIdx.x * blockDim.x + threadIdx.x;   // float2 index
    int total = N * (F / 2);
    if (i >= total) return;
    int n = i / (F / 2);
    float add = addbuf[n];
    float2 m = ((const float2*)memory)[i];
    float2 o;
    o.x = m.x + add;
    o.y = m.y + add;
    ((float2*)out)[i] = o;
}

extern "C" void kernel_launch(void* const* d_in, const int* in_sizes, int n_in,
                              void* d_out, int out_size, void* d_ws, size_t ws_size,
                              hipStream_t stream)
{
    const float* memory     = (const float*)d_in[0];
    const float* node_ts    = (const float*)d_in[1];
    const float* edge_raw   = (const float*)d_in[2];
    const float* edge_ts    = (const float*)d_in[3];
    const float* time_w     = (const float*)d_in[4];
    const float* time_b     = (const float*)d_in[5];
    const float* fc_node_w  = (const float*)d_in[6];
    const float* fc_node_b  = (const float*)d_in[7];
    const float* fc_edge_w  = (const float*)d_in[8];
    const float* fc_edge_b  = (const float*)d_in[9];
    const float* attn_l     = (const float*)d_in[10];
    const float* attn_r     = (const float*)d_in[11];
    const float* attn_e     = (const float*)d_in[12];
    const int*   src        = (const int*)d_in[13];
    const int*   dst        = (const int*)d_in[14];
    float*       out        = (float*)d_out;

    const int N = in_sizes[1];   // node_ts
    const int E = in_sizes[3];   // edge_ts

    // workspace layout (floats):
    // [0,400)        w_node (100 x float4)
    // [400,800)      w_edge (200 x float2)
    // [800,816)      bias
    // [816,+4N)      el_er  (N x float4)
    // [+N)           addbuf
    // ints: cnt[N], offs[N], cursor[N], bsum[256]
    // bucket: E x float4 (16B-aligned)
    float* ws = (float*)d_ws;
    float4* w_node  = (float4*)ws;
    float2* w_edge  = (float2*)(ws + 400);
    float*  bias    = ws + 800;
    float4* el_er   = (float4*)(ws + 816);
    float*  addbuf  = ws + 816 + 4 * (size_t)N;
    int*    cnt     = (int*)(ws + 816 + 5 * (size_t)N);
    int*    offs    = cnt + N;
    int*    cursor  = offs + N;
    int*    bsum    = cursor + N;
    size_t  boff    = 816 + 8 * (size_t)N + 256;
    boff            = (boff + 3) & ~(size_t)3;
    float4* bucket  = (float4*)(ws + boff);

    const int nb = (N + 255) / 256;   // scan blocks (<= 256 required)

    {
        int waves  = 3 * F + 6;
        int blocks = (waves + 3) / 4;
        precompute_kernel<<<blocks, 256, 0, stream>>>(
            fc_node_w, fc_node_b, fc_edge_w, fc_edge_b,
            attn_l, attn_r, attn_e, w_node, w_edge, bias);
    }
    {
        int blocks = (N + 3) / 4;
        node_kernel<<<blocks, 256, 0, stream>>>(
            memory, w_node, bias, el_er, cnt, N);
    }
    {
        int blocks = (E + 255) / 256;
        count_kernel<<<blocks, 256, 0, stream>>>(dst, cnt, E);
    }
    scan1_kernel<<<nb, 256, 0, stream>>>(cnt, offs, bsum, N);
    scan2_kernel<<<1, 256, 0, stream>>>(bsum, nb);
    scan3_kernel<<<nb, 256, 0, stream>>>(offs, bsum, cursor, N);
    {
        int blocks = (E + EPB - 1) / EPB;
        edge_gemv_kernel<<<blocks, 256, 0, stream>>>(
            edge_raw, edge_ts, node_ts, src, dst, time_w, time_b,
            w_edge, bias, el_er, cursor, bucket, E);
    }
    {
        int blocks = (N + 15) / 16;
        reduce_kernel<<<blocks, 256, 0, stream>>>(bucket, offs, cnt, addbuf, N);
    }
    {
        int total  = N * (F / 2);
        int blocks = (total + 255) / 256;
        out_kernel<<<blocks, 256, 0, stream>>>(memory, addbuf, out, N);
    }
}